// Round 2
// baseline (176.352 us; speedup 1.0000x reference)
//
#include <hip/hip_runtime.h>

// RandomCutout: B=32, H=512, W=512, C=3, 2 masks of 128x128 per image.
// out[b,y,x,c] = in[b,y,x,c] unless (y,x) in any clipped mask rect for b.
//
// Layout: one block = one image row. 384 threads x float4 = 1536 floats
// = 512 px * 3 ch = exactly one row. b,y derive from blockIdx only ->
// center loads are scalar (s_load), y-test is a wave-uniform branch.

#define BB 32
#define HH 512
#define WW 512
#define MH 128
#define MW 128
#define ROW4 384                  // float4 per row

__global__ __launch_bounds__(384)
void RandomCutout_59545426592097_kernel(const float4* __restrict__ in,
                                        const int* __restrict__ cys,
                                        const int* __restrict__ cxs,
                                        float4* __restrict__ out) {
    const int blk = blockIdx.x;          // [0, 32*512)
    const int b   = blk >> 9;            // image index  (SGPR)
    const int y   = blk & (HH - 1);      // row index    (SGPR)

    // Uniform center loads -> scalar memory path.
    const int cy0 = cys[b * 2 + 0], cy1 = cys[b * 2 + 1];
    const int cx0 = cxs[b * 2 + 0], cx1 = cxs[b * 2 + 1];

    const int y1a = max(cy0 - MH / 2, 0), y2a = min(cy0 + MH / 2, HH);
    const int y1b = max(cy1 - MH / 2, 0), y2b = min(cy1 + MH / 2, HH);

    const bool yin_a = (y >= y1a) & (y < y2a);   // block-uniform
    const bool yin_b = (y >= y1b) & (y < y2b);

    const int g = blk * ROW4 + threadIdx.x;      // float4 index, coalesced
    float4 v = in[g];

    if (yin_a | yin_b) {                         // wave-uniform branch
        const int x1a = max(cx0 - MW / 2, 0), x2a = min(cx0 + MW / 2, WW);
        const int x1b = max(cx1 - MW / 2, 0), x2b = min(cx1 + MW / 2, WW);

        const int off = threadIdx.x * 4;         // float offset in row [0,1536)
        const int xc0 = (off + 0) / 3;           // column per float (/3 magic-mul)
        const int xc1 = (off + 1) / 3;
        const int xc2 = (off + 2) / 3;
        const int xc3 = (off + 3) / 3;

        const bool cut0 = (yin_a & (xc0 >= x1a) & (xc0 < x2a)) | (yin_b & (xc0 >= x1b) & (xc0 < x2b));
        const bool cut1 = (yin_a & (xc1 >= x1a) & (xc1 < x2a)) | (yin_b & (xc1 >= x1b) & (xc1 < x2b));
        const bool cut2 = (yin_a & (xc2 >= x1a) & (xc2 < x2a)) | (yin_b & (xc2 >= x1b) & (xc2 < x2b));
        const bool cut3 = (yin_a & (xc3 >= x1a) & (xc3 < x2a)) | (yin_b & (xc3 >= x1b) & (xc3 < x2b));

        if (cut0) v.x = 0.0f;
        if (cut1) v.y = 0.0f;
        if (cut2) v.z = 0.0f;
        if (cut3) v.w = 0.0f;
    }

    out[g] = v;
}

extern "C" void kernel_launch(void* const* d_in, const int* in_sizes, int n_in,
                              void* d_out, int out_size, void* d_ws, size_t ws_size,
                              hipStream_t stream) {
    const float4* in  = (const float4*)d_in[0];
    const int*    cys = (const int*)d_in[1];
    const int*    cxs = (const int*)d_in[2];
    float4*       out = (float4*)d_out;

    const int blocks  = BB * HH;   // 16384 blocks, one per row
    const int threads = ROW4;      // 384 = 6 waves
    RandomCutout_59545426592097_kernel<<<blocks, threads, 0, stream>>>(in, cys, cxs, out);
}